// Round 1
// baseline (6921.128 us; speedup 1.0000x reference)
//
#include <hip/hip_runtime.h>
#include <hip/hip_bf16.h>

// ---------------- types ----------------
typedef __attribute__((ext_vector_type(8))) short bf16x8;   // 8 x bf16 (4 VGPRs)
typedef __attribute__((ext_vector_type(4))) float f32x4;

#define MFMA16(a,b,c) __builtin_amdgcn_mfma_f32_16x16x32_bf16((a),(b),(c),0,0,0)

__device__ __forceinline__ float sigmf(float x){ return 1.f/(1.f + __expf(-x)); }
__device__ __forceinline__ float tanh_fast(float x){
    float e = __expf(-2.f*fabsf(x));
    float t = (1.f-e)/(1.f+e);
    return x < 0.f ? -t : t;
}

// ---------------- problem constants ----------------
#define B_   64
#define T_   512
#define H_   1000
#define HP   1024        // padded H
#define G3   3072        // 3*HP
#define NC_  2000
#define FEAT_C 500
#define FEAT_P 512
#define NROWS 32768      // B_*T_

// ---------------- ws layout (bytes) ----------------
#define OFF_FEAT  ((size_t)0)                       // 32768*512*2      = 33,554,432
#define OFF_WIHF  (OFF_FEAT + 33554432ull)          // 3072*512*2
#define OFF_WIHB  (OFF_WIHF + 3145728ull)
#define OFF_WHH   (OFF_WIHB + 3145728ull)           // [2][3072][1024] bf16 = 12,582,912
#define OFF_LINW  (OFF_WHH + 12582912ull)           // 2000*2048*2 = 8,192,000
#define OFF_BIHF  (OFF_LINW + 8192000ull)           // 3072*4
#define OFF_BIHB  (OFF_BIHF + 12288ull)
#define OFF_BHH   (OFF_BIHB + 12288ull)             // [2][3072] f32 = 24,576
#define OFF_XP    (OFF_BHH + 24576ull)              // [2][32768][3072] bf16 = 402,653,184
#define OFF_HFP   (OFF_XP + 402653184ull)           // [2*64][1024] f32 = 524,288
#define OFF_HBF   (OFF_HFP + 524288ull)             // [2 parity][2*64][1024] bf16 = 524,288
#define OFF_HCAT  (OFF_HBF + 524288ull)             // [64][2048] bf16 = 262,144
#define WS_NEED   (OFF_HCAT + 262144ull)

// ---------------- weight prep ----------------
// chunked pad: src [3*1000][C] -> dst [3*1024][Cp], zero pad rows(j>=1000)/cols(c>=C)
__global__ void cvt_pad_3h(const float* __restrict__ src, __hip_bfloat16* __restrict__ dst,
                           int C, int Cp) {
    size_t i = (size_t)blockIdx.x*blockDim.x + threadIdx.x;
    size_t total = (size_t)G3 * Cp;
    if (i >= total) return;
    int r = (int)(i / Cp), c = (int)(i % Cp);
    int chunk = r >> 10, j = r & 1023;
    float v = (j < H_ && c < C) ? src[((size_t)chunk*H_ + j)*C + c] : 0.f;
    dst[i] = __float2bfloat16(v);
}

// plain pad (lin_w): src [R][C] -> dst [R][Cp]
__global__ void cvt_pad(const float* __restrict__ src, __hip_bfloat16* __restrict__ dst,
                        int R, int C, int Cp) {
    size_t i = (size_t)blockIdx.x*blockDim.x + threadIdx.x;
    size_t total = (size_t)R * Cp;
    if (i >= total) return;
    int r = (int)(i / Cp), c = (int)(i % Cp);
    float v = (c < C) ? src[(size_t)r*C + c] : 0.f;
    dst[i] = __float2bfloat16(v);
}

__global__ void pad_b3h(const float* __restrict__ src, float* __restrict__ dst) {
    int i = blockIdx.x*blockDim.x + threadIdx.x;
    if (i >= G3) return;
    int chunk = i >> 10, j = i & 1023;
    dst[i] = (j < H_) ? src[chunk*H_ + j] : 0.f;
}

// ---------------- embedding gather ----------------
__global__ __launch_bounds__(256)
void embed_k(const int* __restrict__ wi, const int* __restrict__ pi, const int* __restrict__ ii,
             const int* __restrict__ ti, const int* __restrict__ mi,
             const float* __restrict__ we, const float* __restrict__ pe, const float* __restrict__ ie,
             const float* __restrict__ te, const float* __restrict__ me,
             __hip_bfloat16* __restrict__ feat) {
    int r = blockIdx.x;          // b*512 + t, matches [B,T] row-major idx arrays
    int iw = wi[r], ip = pi[r], ib = ii[r], it = ti[r], im = mi[r];
    #pragma unroll
    for (int q = 0; q < 2; ++q) {
        int c = threadIdx.x + q*256;
        float v;
        if      (c < 300) v = we[(size_t)iw*300 + c];
        else if (c < 350) v = pe[ip*50 + (c-300)];
        else if (c < 400) v = ie[ib*50 + (c-350)];
        else if (c < 450) v = te[it*50 + (c-400)];
        else if (c < 500) v = me[im*50 + (c-450)];
        else              v = 0.f;
        feat[(size_t)r*FEAT_P + c] = __float2bfloat16(v);
    }
}

// ---------------- input projection GEMM (bf16 MFMA, 128x128x64 tiles) ----------------
// out row r = t*64+b ; A row gathered: b*512 + (dir? clamp(len[b]-1-t,0,511) : t)
__global__ __launch_bounds__(256)
void gemm_xp(const __hip_bfloat16* __restrict__ feat,  // [32768][512]
             const __hip_bfloat16* __restrict__ W,     // [3072][512]
             const float* __restrict__ bias,           // [3072]
             const int* __restrict__ lengths,
             __hip_bfloat16* __restrict__ xp,          // [32768][3072]
             int dir) {
    __shared__ char smem_raw[32768];
    __hip_bfloat16* As = (__hip_bfloat16*)smem_raw;            // [128][64]
    __hip_bfloat16* Bs = (__hip_bfloat16*)(smem_raw + 16384);  // [128][64]
    const int tid = threadIdx.x;
    const int wave = tid >> 6, lane = tid & 63;
    const int bm = blockIdx.x, bn = blockIdx.y;
    const int wm = wave >> 1, wn = wave & 1;

    int arow_src[4];
    #pragma unroll
    for (int q = 0; q < 4; ++q) {
        int flat = q*256 + tid;
        int row = flat >> 3;
        int r_g = bm*128 + row;
        int t = r_g >> 6, b = r_g & 63;
        int src_t;
        if (dir == 0) src_t = t;
        else { int L = lengths[b]; src_t = L - 1 - t; src_t = src_t < 0 ? 0 : src_t; }
        arow_src[q] = b*T_ + src_t;
    }

    f32x4 acc[4][4];
    #pragma unroll
    for (int i = 0; i < 4; ++i)
        #pragma unroll
        for (int j = 0; j < 4; ++j) acc[i][j] = (f32x4){0.f,0.f,0.f,0.f};

    for (int kt = 0; kt < 8; ++kt) {
        int k0 = kt*64;
        #pragma unroll
        for (int q = 0; q < 4; ++q) {
            int flat = q*256 + tid;
            int row = flat >> 3, c8 = flat & 7;
            bf16x8 va = *(const bf16x8*)(feat + (size_t)arow_src[q]*FEAT_P + k0 + c8*8);
            bf16x8 vb = *(const bf16x8*)(W + (size_t)(bn*128 + row)*FEAT_P + k0 + c8*8);
            *(bf16x8*)(As + row*64 + c8*8) = va;
            *(bf16x8*)(Bs + row*64 + c8*8) = vb;
        }
        __syncthreads();
        #pragma unroll
        for (int ks = 0; ks < 2; ++ks) {
            bf16x8 af[4], bfr[4];
            #pragma unroll
            for (int i = 0; i < 4; ++i)
                af[i] = *(const bf16x8*)(As + (wm*64 + i*16 + (lane&15))*64 + ks*32 + (lane>>4)*8);
            #pragma unroll
            for (int j = 0; j < 4; ++j)
                bfr[j] = *(const bf16x8*)(Bs + (wn*64 + j*16 + (lane&15))*64 + ks*32 + (lane>>4)*8);
            #pragma unroll
            for (int i = 0; i < 4; ++i)
                #pragma unroll
                for (int j = 0; j < 4; ++j)
                    acc[i][j] = MFMA16(af[i], bfr[j], acc[i][j]);
        }
        __syncthreads();
    }

    // epilogue: +bias, bf16, LDS repack for coalesced 16B stores
    __hip_bfloat16* Cs = (__hip_bfloat16*)smem_raw;  // [128][128]
    #pragma unroll
    for (int j = 0; j < 4; ++j) {
        int col_l = wn*64 + j*16 + (lane & 15);
        float bs = bias[bn*128 + col_l];
        #pragma unroll
        for (int i = 0; i < 4; ++i) {
            #pragma unroll
            for (int r = 0; r < 4; ++r) {
                int row_l = wm*64 + i*16 + (lane>>4)*4 + r;
                Cs[row_l*128 + col_l] = __float2bfloat16(acc[i][j][r] + bs);
            }
        }
    }
    __syncthreads();
    #pragma unroll
    for (int q = 0; q < 8; ++q) {
        int flat = q*256 + tid;       // 16B units, 2048 total
        int row = flat >> 4, c8 = flat & 15;
        bf16x8 v = *(const bf16x8*)(Cs + row*128 + c8*8);
        *(bf16x8*)(xp + (size_t)(bm*128 + row)*G3 + bn*128 + c8*8) = v;
    }
}

// ---------------- h init ----------------
__global__ void init_h(const float* __restrict__ hidden, float* __restrict__ hfp,
                       __hip_bfloat16* __restrict__ hbf) {
    int i = blockIdx.x*blockDim.x + threadIdx.x;   // over 2*64*1024
    if (i >= 2*B_*HP) return;
    int row = i >> 10, j = i & 1023;               // row = dir*64+b
    int dir = row >> 6, b = row & 63;
    float v = (j < H_) ? hidden[((size_t)dir*B_ + b)*H_ + j] : 0.f;
    hfp[i] = v;
    __hip_bfloat16 bv = __float2bfloat16(v);
    hbf[i] = bv;                 // parity 0
    hbf[2*B_*HP + i] = bv;       // parity 1
}

// ---------------- one GRU timestep (both directions) ----------------
// grid 256 x 128thr: blk -> dir=blk>>7, ub=(blk>>1)&63 (16 units), bh=blk&1 (32 rows)
// wave (2/block) -> 16 batch rows. acc tiles r/z/n per 16 units x 16 rows.
__global__ __launch_bounds__(128)
void gru_step(const __hip_bfloat16* __restrict__ whh,  // [2][3072][1024]
              const float* __restrict__ bhh,           // [2][3072]
              const __hip_bfloat16* __restrict__ xp,   // [2][32768][3072]
              const int* __restrict__ lengths,
              float* __restrict__ hfp,                 // [2*64][1024]
              __hip_bfloat16* __restrict__ hbf,        // [2][2*64][1024]
              int t) {
    const int blk = blockIdx.x;
    const int dir = blk >> 7;
    const int ub  = (blk >> 1) & 63;
    const int bh  = blk & 1;
    const int wave = threadIdx.x >> 6, lane = threadIdx.x & 63;
    const int rbase = bh*32 + wave*16;
    const int lenmax = lengths[rbase];        // lengths sorted descending
    if (t >= lenmax) return;                  // whole 16-row block frozen; nobody reads it anymore
    const int cur = t & 1, prev = cur ^ 1;

    const __hip_bfloat16* hb = hbf + ((size_t)prev*2*B_ + dir*B_)*HP;
    const __hip_bfloat16* wb = whh + (size_t)dir*G3*HP;
    const int arow = rbase + (lane & 15);
    const int koff = (lane >> 4)*8;
    const int wr = ub*16 + (lane & 15);       // hidden unit / output col

    f32x4 accr = {0.f,0.f,0.f,0.f}, accz = {0.f,0.f,0.f,0.f}, accn = {0.f,0.f,0.f,0.f};
    const __hip_bfloat16* b0p = wb + ((size_t)0*HP + wr)*HP + koff;
    const __hip_bfloat16* b1p = wb + ((size_t)1*HP + wr)*HP + koff;
    const __hip_bfloat16* b2p = wb + ((size_t)2*HP + wr)*HP + koff;
    const __hip_bfloat16* ap  = hb + (size_t)arow*HP + koff;
    for (int ks = 0; ks < 32; ++ks) {
        bf16x8 a  = *(const bf16x8*)(ap  + ks*32);
        bf16x8 b0 = *(const bf16x8*)(b0p + ks*32);
        bf16x8 b1 = *(const bf16x8*)(b1p + ks*32);
        bf16x8 b2 = *(const bf16x8*)(b2p + ks*32);
        accr = MFMA16(a, b0, accr);
        accz = MFMA16(a, b1, accz);
        accn = MFMA16(a, b2, accn);
    }

    const int j = wr;
    const float bhr = bhh[dir*G3 + j];
    const float bhz = bhh[dir*G3 + HP + j];
    const float bhn = bhh[dir*G3 + 2*HP + j];
    const __hip_bfloat16* xrow = xp + ((size_t)dir*NROWS + (size_t)t*B_)*G3;
    #pragma unroll
    for (int r = 0; r < 4; ++r) {
        int b_ = rbase + (lane >> 4)*4 + r;
        int lb = lengths[b_];
        size_t hidx = ((size_t)dir*B_ + b_)*HP + j;
        float hprev = hfp[hidx];
        float hnew;
        if (t < lb) {
            float xr = __bfloat162float(xrow[(size_t)b_*G3 + j]);
            float xz = __bfloat162float(xrow[(size_t)b_*G3 + HP + j]);
            float xn = __bfloat162float(xrow[(size_t)b_*G3 + 2*HP + j]);
            float rr = sigmf(xr + accr[r] + bhr);
            float zz = sigmf(xz + accz[r] + bhz);
            float nn = tanh_fast(xn + rr*(accn[r] + bhn));
            hnew = (1.f - zz)*nn + zz*hprev;
            hfp[hidx] = hnew;
        } else {
            hnew = hprev;   // frozen (packed-sequence semantics)
        }
        hbf[((size_t)cur*2*B_ + dir*B_ + b_)*HP + j] = __float2bfloat16(hnew);
    }
}

// ---------------- hcat build ----------------
__global__ void hcat_k(const float* __restrict__ hfp, __hip_bfloat16* __restrict__ hcat) {
    int i = blockIdx.x*blockDim.x + threadIdx.x;   // 64*2048
    if (i >= B_*2048) return;
    int b = i >> 11, j = i & 2047;
    float v = 0.f;
    if (j < H_)            v = hfp[(size_t)b*HP + j];
    else if (j < 2*H_)     v = hfp[(size_t)(B_ + b)*HP + (j - H_)];
    hcat[i] = __float2bfloat16(v);
}

// ---------------- final linear + BN ----------------
__global__ __launch_bounds__(256)
void lin_bn_k(const __hip_bfloat16* __restrict__ hcat,  // [64][2048]
              const __hip_bfloat16* __restrict__ linw,  // [2000][2048]
              const float* __restrict__ lin_b, const float* __restrict__ gamma,
              const float* __restrict__ beta, const float* __restrict__ mean,
              const float* __restrict__ var,
              float* __restrict__ out) {                // [64][2000]
    __shared__ __hip_bfloat16 wlds[16*2056];            // +8 pad: kills 16-way bank conflict
    const int n0 = blockIdx.x*16;
    const int tid = threadIdx.x;
    #pragma unroll
    for (int q = 0; q < 16; ++q) {
        int flat8 = q*256 + tid;       // 16B units, 4096 total
        int row = flat8 >> 8, c8 = flat8 & 255;
        bf16x8 v = *(const bf16x8*)(linw + (size_t)(n0+row)*2048 + c8*8);
        *(bf16x8*)(wlds + row*2056 + c8*8) = v;
    }
    __syncthreads();
    const int wave = tid >> 6, lane = tid & 63;
    const int mrow = wave*16 + (lane & 15);
    f32x4 acc = {0.f,0.f,0.f,0.f};
    for (int ks = 0; ks < 64; ++ks) {
        bf16x8 a = *(const bf16x8*)(hcat + (size_t)mrow*2048 + ks*32 + (lane>>4)*8);
        bf16x8 b = *(const bf16x8*)(wlds + (lane&15)*2056 + ks*32 + (lane>>4)*8);
        acc = MFMA16(a, b, acc);
    }
    const int c = n0 + (lane & 15);
    const float g = gamma[c], bt = beta[c], mn = mean[c], lb = lin_b[c];
    const float iv = rsqrtf(var[c] + 1e-5f);
    #pragma unroll
    for (int r = 0; r < 4; ++r) {
        int b_ = wave*16 + (lane>>4)*4 + r;
        float logit = acc[r] + lb;
        out[(size_t)b_*NC_ + c] = g*(logit - mn)*iv + bt;
    }
}

// ---------------- hidden copy ----------------
__global__ void hid_out(const float* __restrict__ hfp, float* __restrict__ out) {
    int i = blockIdx.x*blockDim.x + threadIdx.x;   // 2*64*1000
    if (i >= 2*B_*H_) return;
    int j = i % H_, row = i / H_;
    out[B_*NC_ + i] = hfp[(size_t)row*HP + j];
}

// ---------------- host ----------------
extern "C" void kernel_launch(void* const* d_in, const int* in_sizes, int n_in,
                              void* d_out, int out_size, void* d_ws, size_t ws_size,
                              hipStream_t stream) {
    const int*   wi      = (const int*)d_in[0];
    const int*   pi      = (const int*)d_in[1];
    const int*   ii      = (const int*)d_in[2];
    const int*   ti      = (const int*)d_in[3];
    const int*   mi      = (const int*)d_in[4];
    const int*   lengths = (const int*)d_in[5];
    const float* hidden  = (const float*)d_in[6];
    const float* we      = (const float*)d_in[7];
    const float* pe      = (const float*)d_in[8];
    const float* ie      = (const float*)d_in[9];
    const float* te      = (const float*)d_in[10];
    const float* me      = (const float*)d_in[11];
    const float* w_ih_f  = (const float*)d_in[12];
    const float* w_hh_f  = (const float*)d_in[13];
    const float* b_ih_f  = (const float*)d_in[14];
    const float* b_hh_f  = (const float*)d_in[15];
    const float* w_ih_b  = (const float*)d_in[16];
    const float* w_hh_b  = (const float*)d_in[17];
    const float* b_ih_b  = (const float*)d_in[18];
    const float* b_hh_b  = (const float*)d_in[19];
    const float* lin_w   = (const float*)d_in[20];
    const float* lin_b   = (const float*)d_in[21];
    const float* gamma   = (const float*)d_in[22];
    const float* beta    = (const float*)d_in[23];
    const float* mean    = (const float*)d_in[24];
    const float* var     = (const float*)d_in[25];
    float* out = (float*)d_out;

    if (ws_size < WS_NEED) return;  // fail loudly via validation rather than corrupt

    char* ws = (char*)d_ws;
    __hip_bfloat16* FEAT = (__hip_bfloat16*)(ws + OFF_FEAT);
    __hip_bfloat16* WIHF = (__hip_bfloat16*)(ws + OFF_WIHF);
    __hip_bfloat16* WIHB = (__hip_bfloat16*)(ws + OFF_WIHB);
    __hip_bfloat16* WHH  = (__hip_bfloat16*)(ws + OFF_WHH);   // [2][3072][1024]
    __hip_bfloat16* LINW = (__hip_bfloat16*)(ws + OFF_LINW);
    float* BIHF = (float*)(ws + OFF_BIHF);
    float* BIHB = (float*)(ws + OFF_BIHB);
    float* BHH  = (float*)(ws + OFF_BHH);                      // [2][3072]
    __hip_bfloat16* XP   = (__hip_bfloat16*)(ws + OFF_XP);     // [2][32768][3072]
    float* HFP = (float*)(ws + OFF_HFP);
    __hip_bfloat16* HBF  = (__hip_bfloat16*)(ws + OFF_HBF);
    __hip_bfloat16* HCAT = (__hip_bfloat16*)(ws + OFF_HCAT);

    // weight prep
    cvt_pad_3h<<<(G3*512 + 255)/256, 256, 0, stream>>>(w_ih_f, WIHF, FEAT_C, FEAT_P);
    cvt_pad_3h<<<(G3*512 + 255)/256, 256, 0, stream>>>(w_ih_b, WIHB, FEAT_C, FEAT_P);
    cvt_pad_3h<<<(G3*1024 + 255)/256, 256, 0, stream>>>(w_hh_f, WHH, H_, HP);
    cvt_pad_3h<<<(G3*1024 + 255)/256, 256, 0, stream>>>(w_hh_b, WHH + (size_t)G3*HP, H_, HP);
    cvt_pad<<<(NC_*2048 + 255)/256, 256, 0, stream>>>(lin_w, LINW, NC_, NC_, 2048);
    pad_b3h<<<(G3 + 255)/256, 256, 0, stream>>>(b_ih_f, BIHF);
    pad_b3h<<<(G3 + 255)/256, 256, 0, stream>>>(b_ih_b, BIHB);
    pad_b3h<<<(G3 + 255)/256, 256, 0, stream>>>(b_hh_f, BHH);
    pad_b3h<<<(G3 + 255)/256, 256, 0, stream>>>(b_hh_b, BHH + G3);

    // embeddings
    embed_k<<<NROWS, 256, 0, stream>>>(wi, pi, ii, ti, mi, we, pe, ie, te, me, FEAT);

    // input projections (both directions)
    dim3 gg(NROWS/128, G3/128);
    gemm_xp<<<gg, 256, 0, stream>>>(FEAT, WIHF, BIHF, lengths, XP, 0);
    gemm_xp<<<gg, 256, 0, stream>>>(FEAT, WIHB, BIHB, lengths, XP + (size_t)NROWS*G3, 1);

    // recurrence
    init_h<<<(2*B_*HP + 255)/256, 256, 0, stream>>>(hidden, HFP, HBF);
    for (int t = 0; t < T_; ++t)
        gru_step<<<256, 128, 0, stream>>>(WHH, BHH, XP, lengths, HFP, HBF, t);

    // head
    hcat_k<<<(B_*2048 + 255)/256, 256, 0, stream>>>(HFP, HCAT);
    lin_bn_k<<<NC_/16, 256, 0, stream>>>(HCAT, LINW, lin_b, gamma, beta, mean, var, out);
    hid_out<<<(2*B_*H_ + 255)/256, 256, 0, stream>>>(HFP, out);
}